// Round 12
// baseline (690.069 us; speedup 1.0000x reference)
//
#include <hip/hip_runtime.h>
#include <hip/hip_bf16.h>
#include <stdint.h>

typedef unsigned short ushort_t;
typedef uint32_t u32;
typedef __attribute__((ext_vector_type(8))) __bf16 bf16x8;
typedef __attribute__((ext_vector_type(8))) unsigned short u16x8;
typedef __attribute__((ext_vector_type(4))) float f32x4;

#define T_  256
#define H_  2048
#define E_  60
#define F_  1408
#define FS_ 5632

__device__ __forceinline__ u32 rne2(float lo, float hi){
  u32 a = __builtin_bit_cast(u32, lo);
  u32 b = __builtin_bit_cast(u32, hi);
  a += 0x7FFFu + ((a >> 16) & 1u);
  b += 0x7FFFu + ((b >> 16) & 1u);
  return (a >> 16) | (b & 0xFFFF0000u);
}
__device__ __forceinline__ ushort_t rne1(float f){
  u32 a = __builtin_bit_cast(u32, f);
  a += 0x7FFFu + ((a >> 16) & 1u);
  return (ushort_t)(a >> 16);
}
__device__ __forceinline__ f32x4 zero4(){ f32x4 z; z[0]=0.f; z[1]=0.f; z[2]=0.f; z[3]=0.f; return z; }

__device__ __forceinline__ bf16x8 ldsbS(const float* p, const int S){
  union { u32 u[4]; bf16x8 v; } cv;
  cv.u[0] = rne2(p[0],   p[S]);
  cv.u[1] = rne2(p[2*S], p[3*S]);
  cv.u[2] = rne2(p[4*S], p[5*S]);
  cv.u[3] = rne2(p[6*S], p[7*S]);
  return cv.v;
}
__device__ __forceinline__ bf16x8 loada(const ushort_t* p){
  return __builtin_bit_cast(bf16x8, *(const u16x8*)p);
}
__device__ __forceinline__ void gload16(const float* g, float* l){
  __builtin_amdgcn_global_load_lds(
      (const __attribute__((address_space(1))) void*)g,
      (__attribute__((address_space(3))) void*)l, 16, 0, 0);
}
#define MFMA(a,b,c) __builtin_amdgcn_mfma_f32_16x16x32_bf16((a),(b),(c),0,0,0)

#define VMW(n)  asm volatile("s_waitcnt vmcnt(" #n ")" ::: "memory")
#define BARM()  asm volatile("s_barrier" ::: "memory")
#define SCH()   __builtin_amdgcn_sched_barrier(0)

// ---------------- K1: router -------------------------------------------------------
__global__ __launch_bounds__(256) void k_router(
    const float* __restrict__ x, const float* __restrict__ gw,
    const float* __restrict__ sgw, ushort_t* __restrict__ xb,
    int* __restrict__ tk_idx, float* __restrict__ tk_val, float* __restrict__ sig)
{
  const int t = blockIdx.x, tid = threadIdx.x;
  const float* xr = x + (size_t)t * H_;
  {
    const float4 v0 = *(const float4*)(xr + tid*8);
    const float4 v1 = *(const float4*)(xr + tid*8 + 4);
    u32* dst = (u32*)(xb + (size_t)t*H_ + tid*8);
    dst[0] = rne2(v0.x, v0.y); dst[1] = rne2(v0.z, v0.w);
    dst[2] = rne2(v1.x, v1.y); dst[3] = rne2(v1.z, v1.w);
  }
  __shared__ float s_part[4][64];
  __shared__ float s_logit[64];
  __shared__ float s_red[256];
  const int e = tid & 63, q = tid >> 6;
  float p = 0.f;
  if (e < E_) {
    const float* g = gw + e;
    for (int h = q*512; h < q*512 + 512; ++h) p += xr[h] * g[h*E_];
  }
  s_part[q][e] = p;
  float sp = 0.f;
  for (int h = tid; h < H_; h += 256) sp += xr[h] * sgw[h];
  s_red[tid] = sp;
  __syncthreads();
  if (tid < 64) s_logit[tid] = s_part[0][tid] + s_part[1][tid] + s_part[2][tid] + s_part[3][tid];
  for (int s = 128; s > 0; s >>= 1) {
    if (tid < s) s_red[tid] += s_red[tid + s];
    __syncthreads();
  }
  if (tid == 0) {
    sig[t] = 1.f / (1.f + expf(-s_red[0]));
    float mx = -3.4e38f;
    for (int i = 0; i < E_; ++i) mx = fmaxf(mx, s_logit[i]);
    float sum = 0.f;
    for (int i = 0; i < E_; ++i) sum += expf(s_logit[i] - mx);
    for (int k = 0; k < 4; ++k) {
      float bv = -3.4e38f; int bi = 0;
      for (int i = 0; i < E_; ++i) { float v = s_logit[i]; if (v > bv) { bv = v; bi = i; } }
      tk_idx[t*4 + k] = bi;
      tk_val[t*4 + k] = expf(bv - mx) / sum;
      s_logit[bi] = -3.4e38f;
    }
  }
}

// ---------------- K2: per-expert token lists ---------------------------------------
__global__ __launch_bounds__(256) void k_lists(
    const int* __restrict__ tk_idx, const float* __restrict__ tk_val,
    int* __restrict__ cnt, int* __restrict__ ltok,
    int* __restrict__ lpair, float* __restrict__ lwt)
{
  __shared__ int   s_idx[1024];
  __shared__ float s_val[1024];
  const int tid = threadIdx.x;
  for (int i = tid; i < 1024; i += 256) { s_idx[i] = tk_idx[i]; s_val[i] = tk_val[i]; }
  __syncthreads();
  const int e = tid;
  if (e >= E_) return;
  int c = 0;
  for (int i = 0; i < 1024; ++i) {
    if (s_idx[i] == e && c < 64) {
      ltok[e*64 + c]  = i >> 2;
      lpair[e*64 + c] = i;
      lwt[e*64 + c]   = s_val[i];
      ++c;
    }
  }
  cnt[e] = c;
}

// ---------------- MEGA1: gu' (480 blocks, N=176) + sh_gu' (88 blocks, N=64) --------
__global__ __launch_bounds__(512) void k_mega1(
    const ushort_t* __restrict__ xb,
    const float* __restrict__ wg_all, const float* __restrict__ wu_all,
    const int* __restrict__ cnt, const int* __restrict__ ltok,
    const float* __restrict__ lwt, ushort_t* __restrict__ act,
    const float* __restrict__ swg, const float* __restrict__ swu,
    ushort_t* __restrict__ acts)
{
  __shared__ char smem[94208];   // gu': 2 x 45056 dbuf + 4KB scratch; sh: first 32KB
  float* lds = (float*)smem;
  const int bid = blockIdx.x;
  const int tid = threadIdx.x, wave = tid >> 6, lane = tid & 63;
  const int ln15 = lane & 15, kg = lane >> 4;

  if (bid < 480) {
    // ---- expert gate/up: N=176 (704B chunks), BK=32, 64 steps, dbuf 90KB ----
    const int e  = bid >> 3;
    const int cx = bid & 7;
    int m = cnt[e];
    if (m == 0) return;
    if (m > 64) m = 64;
    const int col0 = cx * 176;
    const size_t wbase = (size_t)e * ((size_t)H_ * F_) + col0;
    const char* gsg = (const char*)(wg_all + wbase);
    const char* gsu = (const char*)(wu_all + wbase);
    const int nreal = (wave < 4) ? 6 : 5;
    const int sbeg  = (wave < 4) ? 6*wave : 24 + 5*(wave - 4);
    const int has2  = (wave < 3);           // second n-tile (tiles 8,9,10)
    const int n0c = wave*16, n1c = (wave+8)*16;

    const ushort_t* ap[4];
    #pragma unroll
    for (int rt = 0; rt < 4; ++rt) {
      int row = rt*16 + ln15;
      int tok = ltok[e*64 + (row < m ? row : m-1)];
      ap[rt] = xb + (size_t)tok * H_ + kg*8;
    }

    f32x4 ag[4][2], au[4][2];
    #pragma unroll
    for (int i = 0; i < 4; ++i) { ag[i][0]=zero4(); ag[i][1]=zero4(); au[i][0]=zero4(); au[i][1]=zero4(); }
    bf16x8 a0[4], a1[4];

#define GU2_STAGE(B, K0) do { \
    _Pragma("unroll") for (int n_ = 0; n_ < 6; ++n_) { \
      if (n_ < nreal) { \
        int i_ = sbeg + n_; \
        int off_ = i_*1024 + (lane<<4); \
        int mo_ = (i_ < 22) ? off_ : off_ - 22528; \
        int row_ = mo_ / 704; \
        int colb_ = mo_ - row_*704; \
        const char* s_ = ((i_ < 22) ? gsg : gsu) + (size_t)((K0) + row_)*(F_*4) + colb_; \
        gload16((const float*)s_, (float*)(smem + (B)*45056 + i_*1024)); \
      } else { \
        const char* s_ = gsg + (size_t)(K0)*(F_*4) + (lane<<4); \
        gload16((const float*)s_, (float*)(smem + 90112 + (wave-4)*1024)); \
      } \
    } } while(0)
#define GU2_ALOAD(D, K0) do { \
    _Pragma("unroll") for (int rt = 0; rt < 4; ++rt) D[rt] = loada(ap[rt] + (K0)); } while(0)
#define GU2_COMPUTE(B, A) do { \
    const float* bb_ = lds + (B)*11264 + kg*8*176; \
    bf16x8 bg0_ = ldsbS(bb_ + n0c + ln15, 176); \
    bf16x8 bu0_ = ldsbS(bb_ + 5632 + n0c + ln15, 176); \
    _Pragma("unroll") for (int rt = 0; rt < 4; ++rt) { \
      ag[rt][0] = MFMA(A[rt], bg0_, ag[rt][0]); \
      au[rt][0] = MFMA(A[rt], bu0_, au[rt][0]); \
    } \
    if (has2) { \
      bf16x8 bg1_ = ldsbS(bb_ + n1c + ln15, 176); \
      bf16x8 bu1_ = ldsbS(bb_ + 5632 + n1c + ln15, 176); \
      _Pragma("unroll") for (int rt = 0; rt < 4; ++rt) { \
        ag[rt][1] = MFMA(A[rt], bg1_, ag[rt][1]); \
        au[rt][1] = MFMA(A[rt], bu1_, au[rt][1]); \
      } \
    } } while(0)

    GU2_ALOAD(a0, 0);  GU2_STAGE(0, 0);
    GU2_ALOAD(a1, 32); GU2_STAGE(1, 32);
    for (int t = 0; t + 2 < 64; t += 2) {
      VMW(10); BARM(); SCH();
      GU2_COMPUTE(0, a0);
      BARM();
      GU2_ALOAD(a0, (t+2)*32); GU2_STAGE(0, (t+2)*32);
      VMW(10); BARM(); SCH();
      GU2_COMPUTE(1, a1);
      BARM();
      GU2_ALOAD(a1, (t+3)*32); GU2_STAGE(1, (t+3)*32);
    }
    VMW(10); BARM(); SCH();
    GU2_COMPUTE(0, a0);
    VMW(0); BARM(); SCH();
    GU2_COMPUTE(1, a1);

    #pragma unroll
    for (int nt = 0; nt < 2; ++nt) {
      if (nt == 1 && !has2) break;
      int coln = col0 + (nt ? n1c : n0c) + ln15;
      #pragma unroll
      for (int rt = 0; rt < 4; ++rt)
        #pragma unroll
        for (int j = 0; j < 4; ++j) {
          int r = rt*16 + kg*4 + j;
          if (r < m) {
            float wt = lwt[e*64 + r];
            float g = ag[rt][nt][j], u = au[rt][nt][j];
            float a = g / (1.f + __expf(-g)) * u * wt;
            act[((size_t)e*64 + r) * F_ + coln] = rne1(a);
          }
        }
    }
  } else {
    // ---- shared gate/up: M=256 (8 waves: row-quarter x col-half), N=64 ----
    const int sb = bid - 480;
    const int cb = sb * 64;
    const int wq = wave & 3, wc = wave >> 2;
    const int rowb = wq * 64;
    const char* gG = (const char*)(swg + cb);
    const char* gU = (const char*)(swu + cb);

    const ushort_t* ap[4];
    #pragma unroll
    for (int rt = 0; rt < 4; ++rt)
      ap[rt] = xb + (size_t)(rowb + rt*16 + ln15) * H_ + kg*8;

    f32x4 ag[4][2], au[4][2];
    #pragma unroll
    for (int i = 0; i < 4; ++i) { ag[i][0]=zero4(); ag[i][1]=zero4(); au[i][0]=zero4(); au[i][1]=zero4(); }
    bf16x8 a0[4], a1[4];

#define SG2_STAGE(B, K0) do { \
    _Pragma("unroll") for (int n_ = 0; n_ < 2; ++n_) { \
      int i_ = 2*wave + n_; \
      int row_ = 4*(i_ & 7) + (lane >> 4); \
      int colb_ = (lane & 15) << 4; \
      const char* s_ = ((i_ < 8) ? gG : gU) + (size_t)((K0) + row_)*(FS_*4) + colb_; \
      gload16((const float*)s_, (float*)(smem + (B)*16384 + i_*1024)); \
    } } while(0)
#define SG2_ALOAD(D, K0) do { \
    _Pragma("unroll") for (int rt = 0; rt < 4; ++rt) D[rt] = loada(ap[rt] + (K0)); } while(0)
#define SG2_COMPUTE(B, A) do { \
    const float* bb_ = lds + (B)*4096 + kg*8*64 + wc*32; \
    bf16x8 bg0_ = ldsbS(bb_ + ln15, 64),        bg1_ = ldsbS(bb_ + 16 + ln15, 64); \
    bf16x8 bu0_ = ldsbS(bb_ + 2048 + ln15, 64), bu1_ = ldsbS(bb_ + 2064 + ln15, 64); \
    _Pragma("unroll") for (int rt = 0; rt < 4; ++rt) { \
      ag[rt][0] = MFMA(A[rt], bg0_, ag[rt][0]); \
      ag[rt][1] = MFMA(A[rt], bg1_, ag[rt][1]); \
      au[rt][0] = MFMA(A[rt], bu0_, au[rt][0]); \
      au[rt][1] = MFMA(A[rt], bu1_, au[rt][1]); \
    } } while(0)

    SG2_ALOAD(a0, 0);  SG2_STAGE(0, 0);
    SG2_ALOAD(a1, 32); SG2_STAGE(1, 32);
    for (int t = 0; t + 2 < 64; t += 2) {
      VMW(6); BARM(); SCH();
      SG2_COMPUTE(0, a0);
      BARM();
      SG2_ALOAD(a0, (t+2)*32); SG2_STAGE(0, (t+2)*32);
      VMW(6); BARM(); SCH();
      SG2_COMPUTE(1, a1);
      BARM();
      SG2_ALOAD(a1, (t+3)*32); SG2_STAGE(1, (t+3)*32);
    }
    VMW(6); BARM(); SCH();
    SG2_COMPUTE(0, a0);
    VMW(0); BARM(); SCH();
    SG2_COMPUTE(1, a1);

    #pragma unroll
    for (int rt = 0; rt < 4; ++rt)
      #pragma unroll
      for (int nt = 0; nt < 2; ++nt)
        #pragma unroll
        for (int j = 0; j < 4; ++j) {
          int row = rowb + rt*16 + kg*4 + j;
          float g = ag[rt][nt][j], u = au[rt][nt][j];
          acts[(size_t)row * FS_ + cb + wc*32 + nt*16 + ln15] = rne1(g / (1.f + __expf(-g)) * u);
        }
  }
}

// ---------------- MEGA2: down' (240 blocks, N=512) + sh_down' (64 blocks, N=128) ---
__global__ __launch_bounds__(512) void k_mega2(
    const ushort_t* __restrict__ act, const float* __restrict__ wd_all,
    const int* __restrict__ cnt, const int* __restrict__ lpair,
    float* __restrict__ out4,
    const ushort_t* __restrict__ acts, const float* __restrict__ swd,
    float* __restrict__ acc4)
{
  __shared__ char smem[131072];  // down': 2 x 64KB dbuf; sh: first 32KB
  __shared__ int s_pair[64];
  float* lds = (float*)smem;
  const int bid = blockIdx.x;
  const int tid = threadIdx.x, wave = tid >> 6, lane = tid & 63;
  const int ln15 = lane & 15, kg = lane >> 4;

  if (bid < 240) {
    // ---- expert down: N=512 (2KB chunks), BK=32, 44 steps, dbuf 128KB ----
    const int e  = bid >> 2;
    const int cx = bid & 3;
    int m = cnt[e];
    if (m == 0) return;
    if (m > 64) m = 64;
    if (tid < 64) s_pair[tid] = (tid < m) ? lpair[e*64 + tid] : 0;
    const int col0 = cx * 512;
    const char* gsd = (const char*)(wd_all + (size_t)e * ((size_t)F_ * H_) + col0);
    const int c0 = wave * 64;

    const ushort_t* ap[4];
    #pragma unroll
    for (int rt = 0; rt < 4; ++rt)
      ap[rt] = act + ((size_t)e*64 + rt*16 + ln15) * F_ + kg*8;

    f32x4 ac[4][4];
    #pragma unroll
    for (int i = 0; i < 4; ++i)
      #pragma unroll
      for (int c = 0; c < 4; ++c) ac[i][c] = zero4();
    bf16x8 a0[4], a1[4];

// tile i_ holds bytes [i_*1024, i_*1024+1024) of the [32 rows][2048 B] K-tile:
// row = i_>>1, col-half = i_&1, lane offset lane*16 (matches linear LDS dest).
#define DN2_STAGE(B, K0) do { \
    _Pragma("unroll") for (int n_ = 0; n_ < 8; ++n_) { \
      int i_ = wave + n_*8; \
      const char* s_ = gsd + (size_t)((K0) + (i_ >> 1))*(H_*4) + (i_ & 1)*1024 + (lane << 4); \
      gload16((const float*)s_, (float*)(smem + (B)*65536 + i_*1024)); \
    } } while(0)
#define DN2_ALOAD(D, K0) do { \
    _Pragma("unroll") for (int rt = 0; rt < 4; ++rt) D[rt] = loada(ap[rt] + (K0)); } while(0)
#define DN2_COMPUTE(B, A) do { \
    const float* bb_ = lds + (B)*16384 + kg*8*512 + c0; \
    bf16x8 b0_ = ldsbS(bb_ + ln15, 512),      b1_ = ldsbS(bb_ + 16 + ln15, 512); \
    bf16x8 b2_ = ldsbS(bb_ + 32 + ln15, 512), b3_ = ldsbS(bb_ + 48 + ln15, 512); \
    _Pragma("unroll") for (int rt = 0; rt < 4; ++rt) { \
      ac[rt][0] = MFMA(A[rt], b0_, ac[rt][0]); \
      ac[rt][1] = MFMA(A[rt], b1_, ac[rt][1]); \
      ac[rt][2] = MFMA(A[rt], b2_, ac[rt][2]); \
      ac[rt][3] = MFMA(A[rt], b3_, ac[rt][3]); \
    } } while(0)

    DN2_ALOAD(a0, 0);  DN2_STAGE(0, 0);
    DN2_ALOAD(a1, 32); DN2_STAGE(1, 32);
    for (int t = 0; t + 2 < 44; t += 2) {
      VMW(12); BARM(); SCH();
      DN2_COMPUTE(0, a0);
      BARM();
      DN2_ALOAD(a0, (t+2)*32); DN2_STAGE(0, (t+2)*32);
      VMW(12); BARM(); SCH();
      DN2_COMPUTE(1, a1);
      BARM();
      DN2_ALOAD(a1, (t+3)*32); DN2_STAGE(1, (t+3)*32);
    }
    VMW(12); BARM(); SCH();
    DN2_COMPUTE(0, a0);
    VMW(0); BARM(); SCH();
    DN2_COMPUTE(1, a1);

    #pragma unroll
    for (int rt = 0; rt < 4; ++rt)
      #pragma unroll
      for (int c = 0; c < 4; ++c)
        #pragma unroll
        for (int j = 0; j < 4; ++j) {
          int r = rt*16 + kg*4 + j;
          if (r < m)
            out4[(size_t)s_pair[r] * H_ + col0 + c0 + c*16 + ln15] = ac[rt][c][j];
        }
  } else {
    // ---- shared down: M=256 (row-quarter x col-half), each wave 64 rows x 64 cols,
    //      4 col-fragments (FIX: R11 only computed 2 of 4 -> half of acc4 unwritten) ----
    const int sb = bid - 240;
    const int cb = (sb & 15) * 128;
    const int kh = sb >> 4;        // 0..3
    const int wq = wave & 3, wc = wave >> 2;
    const int rowb = wq * 64;
    const char* gsd = (const char*)(swd + (size_t)(kh*1408) * H_ + cb);

    const ushort_t* ap[4];
    #pragma unroll
    for (int rt = 0; rt < 4; ++rt)
      ap[rt] = acts + (size_t)(rowb + rt*16 + ln15) * FS_ + kh*1408 + kg*8;

    f32x4 ac[4][4];
    #pragma unroll
    for (int i = 0; i < 4; ++i)
      #pragma unroll
      for (int c = 0; c < 4; ++c) ac[i][c] = zero4();
    bf16x8 a0[4], a1[4];

#define SD2_STAGE(B, K0) do { \
    _Pragma("unroll") for (int n_ = 0; n_ < 2; ++n_) { \
      int i_ = 2*wave + n_; \
      const char* s_ = gsd + (size_t)((K0) + 2*i_ + (lane >> 5))*(H_*4) + ((lane & 31) << 4); \
      gload16((const float*)s_, (float*)(smem + (B)*16384 + i_*1024)); \
    } } while(0)
#define SD2_ALOAD(D, K0) do { \
    _Pragma("unroll") for (int rt = 0; rt < 4; ++rt) D[rt] = loada(ap[rt] + (K0)); } while(0)
#define SD2_COMPUTE(B, A) do { \
    const float* bb_ = lds + (B)*4096 + kg*8*128 + wc*64; \
    bf16x8 b0_ = ldsbS(bb_ + ln15, 128),      b1_ = ldsbS(bb_ + 16 + ln15, 128); \
    bf16x8 b2_ = ldsbS(bb_ + 32 + ln15, 128), b3_ = ldsbS(bb_ + 48 + ln15, 128); \
    _Pragma("unroll") for (int rt = 0; rt < 4; ++rt) { \
      ac[rt][0] = MFMA(A[rt], b0_, ac[rt][0]); \
      ac[rt][1] = MFMA(A[rt], b1_, ac[rt][1]); \
      ac[rt][2] = MFMA(A[rt], b2_, ac[rt][2]); \
      ac[rt][3] = MFMA(A[rt], b3_, ac[rt][3]); \
    } } while(0)

    SD2_ALOAD(a0, 0);  SD2_STAGE(0, 0);
    SD2_ALOAD(a1, 32); SD2_STAGE(1, 32);
    for (int t = 0; t + 2 < 44; t += 2) {
      VMW(6); BARM(); SCH();
      SD2_COMPUTE(0, a0);
      BARM();
      SD2_ALOAD(a0, (t+2)*32); SD2_STAGE(0, (t+2)*32);
      VMW(6); BARM(); SCH();
      SD2_COMPUTE(1, a1);
      BARM();
      SD2_ALOAD(a1, (t+3)*32); SD2_STAGE(1, (t+3)*32);
    }
    VMW(6); BARM(); SCH();
    SD2_COMPUTE(0, a0);
    VMW(0); BARM(); SCH();
    SD2_COMPUTE(1, a1);

    #pragma unroll
    for (int rt = 0; rt < 4; ++rt)
      #pragma unroll
      for (int c = 0; c < 4; ++c)
        #pragma unroll
        for (int j = 0; j < 4; ++j) {
          int row = rowb + rt*16 + kg*4 + j;
          acc4[((size_t)kh * T_ + row) * H_ + cb + wc*64 + c*16 + ln15] = ac[rt][c][j];
        }
  }
}

// ---------------- K5: combine ------------------------------------------------------
__global__ __launch_bounds__(256) void k_final(
    const float* __restrict__ acc4, const float* __restrict__ out4,
    const float* __restrict__ sig, float* __restrict__ out)
{
  const int idx = blockIdx.x * blockDim.x + threadIdx.x;
  const int t = idx >> 9;
  const int h = (idx & 511) * 4;
  float ox = 0.f, oy = 0.f, oz = 0.f, ow = 0.f;
  #pragma unroll
  for (int s = 0; s < 4; ++s) {
    const float4 v = *(const float4*)(acc4 + ((size_t)s * T_ + t) * H_ + h);
    ox += v.x; oy += v.y; oz += v.z; ow += v.w;
  }
  const float sg = sig[t];
  ox *= sg; oy *= sg; oz *= sg; ow *= sg;
  #pragma unroll
  for (int k = 0; k < 4; ++k) {
    const float4 e4 = *(const float4*)(out4 + (size_t)(t*4 + k) * H_ + h);
    ox += e4.x; oy += e4.y; oz += e4.z; ow += e4.w;
  }
  float4 o; o.x = ox; o.y = oy; o.z = oz; o.w = ow;
  *(float4*)(out + (size_t)t * H_ + h) = o;
}

// ---------------- launch -----------------------------------------------------------
extern "C" void kernel_launch(void* const* d_in, const int* in_sizes, int n_in,
                              void* d_out, int out_size, void* d_ws, size_t ws_size,
                              hipStream_t stream)
{
  (void)in_sizes; (void)n_in; (void)out_size; (void)ws_size;
  const float* x   = (const float*)d_in[0];
  const float* gw  = (const float*)d_in[1];
  const float* wg  = (const float*)d_in[2];
  const float* wu  = (const float*)d_in[3];
  const float* wd  = (const float*)d_in[4];
  const float* swg = (const float*)d_in[5];
  const float* swu = (const float*)d_in[6];
  const float* swd = (const float*)d_in[7];
  const float* sgw = (const float*)d_in[8];

  char* ws = (char*)d_ws;
  ushort_t* xb    = (ushort_t*)(ws);                 // 1,048,576
  ushort_t* act   = (ushort_t*)(ws + 1048576);       // 10,813,440
  ushort_t* acts  = (ushort_t*)(ws + 11862016);      // 2,883,584
  float*    out4  = (float*)   (ws + 14745600);      // 8,388,608
  float*    acc4  = (float*)   (ws + 23134208);      // 8,388,608
  float*    sig   = (float*)   (ws + 31522816);      // 1,024
  int*      tkidx = (int*)     (ws + 31523840);      // 4,096
  float*    tkval = (float*)   (ws + 31527936);      // 4,096
  int*      cnt   = (int*)     (ws + 31532032);      // 256
  int*      ltok  = (int*)     (ws + 31532288);      // 15,360
  int*      lpair = (int*)     (ws + 31547648);      // 15,360
  float*    lwt   = (float*)   (ws + 31563008);      // 15,360

  k_router<<<T_, 256, 0, stream>>>(x, gw, sgw, xb, tkidx, tkval, sig);
  k_lists <<<1, 256, 0, stream>>>(tkidx, tkval, cnt, ltok, lpair, lwt);
  k_mega1 <<<480 + 88, 512, 0, stream>>>(xb, wg, wu, cnt, ltok, lwt, act, swg, swu, acts);
  k_mega2 <<<240 + 64, 512, 0, stream>>>(act, wd, cnt, lpair, out4, acts, swd, acc4);
  k_final <<<512, 256, 0, stream>>>(acc4, out4, sig, (float*)d_out);
}

// Round 13
// 615.688 us; speedup vs baseline: 1.1208x; 1.1208x over previous
//
#include <hip/hip_runtime.h>
#include <hip/hip_bf16.h>
#include <stdint.h>

typedef unsigned short ushort_t;
typedef uint32_t u32;
typedef __attribute__((ext_vector_type(8))) __bf16 bf16x8;
typedef __attribute__((ext_vector_type(8))) unsigned short u16x8;
typedef __attribute__((ext_vector_type(4))) float f32x4;

#define T_  256
#define H_  2048
#define E_  60
#define F_  1408
#define FS_ 5632

__device__ __forceinline__ u32 rne2(float lo, float hi){
  u32 a = __builtin_bit_cast(u32, lo);
  u32 b = __builtin_bit_cast(u32, hi);
  a += 0x7FFFu + ((a >> 16) & 1u);
  b += 0x7FFFu + ((b >> 16) & 1u);
  return (a >> 16) | (b & 0xFFFF0000u);
}
__device__ __forceinline__ ushort_t rne1(float f){
  u32 a = __builtin_bit_cast(u32, f);
  a += 0x7FFFu + ((a >> 16) & 1u);
  return (ushort_t)(a >> 16);
}
__device__ __forceinline__ f32x4 zero4(){ f32x4 z; z[0]=0.f; z[1]=0.f; z[2]=0.f; z[3]=0.f; return z; }

__device__ __forceinline__ bf16x8 ldsbS(const float* p, const int S){
  union { u32 u[4]; bf16x8 v; } cv;
  cv.u[0] = rne2(p[0],   p[S]);
  cv.u[1] = rne2(p[2*S], p[3*S]);
  cv.u[2] = rne2(p[4*S], p[5*S]);
  cv.u[3] = rne2(p[6*S], p[7*S]);
  return cv.v;
}
__device__ __forceinline__ bf16x8 loada(const ushort_t* p){
  return __builtin_bit_cast(bf16x8, *(const u16x8*)p);
}
__device__ __forceinline__ void gload16(const float* g, float* l){
  __builtin_amdgcn_global_load_lds(
      (const __attribute__((address_space(1))) void*)g,
      (__attribute__((address_space(3))) void*)l, 16, 0, 0);
}
#define MFMA(a,b,c) __builtin_amdgcn_mfma_f32_16x16x32_bf16((a),(b),(c),0,0,0)

#define VMW(n)  asm volatile("s_waitcnt vmcnt(" #n ")" ::: "memory")
#define BARM()  asm volatile("s_barrier" ::: "memory")
#define SCH()   __builtin_amdgcn_sched_barrier(0)

// ---------------- K1: router -------------------------------------------------------
__global__ __launch_bounds__(256) void k_router(
    const float* __restrict__ x, const float* __restrict__ gw,
    const float* __restrict__ sgw, ushort_t* __restrict__ xb,
    int* __restrict__ tk_idx, float* __restrict__ tk_val, float* __restrict__ sig)
{
  const int t = blockIdx.x, tid = threadIdx.x;
  const float* xr = x + (size_t)t * H_;
  {
    const float4 v0 = *(const float4*)(xr + tid*8);
    const float4 v1 = *(const float4*)(xr + tid*8 + 4);
    u32* dst = (u32*)(xb + (size_t)t*H_ + tid*8);
    dst[0] = rne2(v0.x, v0.y); dst[1] = rne2(v0.z, v0.w);
    dst[2] = rne2(v1.x, v1.y); dst[3] = rne2(v1.z, v1.w);
  }
  __shared__ float s_part[4][64];
  __shared__ float s_logit[64];
  __shared__ float s_red[256];
  const int e = tid & 63, q = tid >> 6;
  float p = 0.f;
  if (e < E_) {
    const float* g = gw + e;
    for (int h = q*512; h < q*512 + 512; ++h) p += xr[h] * g[h*E_];
  }
  s_part[q][e] = p;
  float sp = 0.f;
  for (int h = tid; h < H_; h += 256) sp += xr[h] * sgw[h];
  s_red[tid] = sp;
  __syncthreads();
  if (tid < 64) s_logit[tid] = s_part[0][tid] + s_part[1][tid] + s_part[2][tid] + s_part[3][tid];
  for (int s = 128; s > 0; s >>= 1) {
    if (tid < s) s_red[tid] += s_red[tid + s];
    __syncthreads();
  }
  if (tid == 0) {
    sig[t] = 1.f / (1.f + expf(-s_red[0]));
    float mx = -3.4e38f;
    for (int i = 0; i < E_; ++i) mx = fmaxf(mx, s_logit[i]);
    float sum = 0.f;
    for (int i = 0; i < E_; ++i) sum += expf(s_logit[i] - mx);
    for (int k = 0; k < 4; ++k) {
      float bv = -3.4e38f; int bi = 0;
      for (int i = 0; i < E_; ++i) { float v = s_logit[i]; if (v > bv) { bv = v; bi = i; } }
      tk_idx[t*4 + k] = bi;
      tk_val[t*4 + k] = expf(bv - mx) / sum;
      s_logit[bi] = -3.4e38f;
    }
  }
}

// ---------------- K2: per-expert token lists ---------------------------------------
__global__ __launch_bounds__(256) void k_lists(
    const int* __restrict__ tk_idx, const float* __restrict__ tk_val,
    int* __restrict__ cnt, int* __restrict__ ltok,
    int* __restrict__ lpair, float* __restrict__ lwt)
{
  __shared__ int   s_idx[1024];
  __shared__ float s_val[1024];
  const int tid = threadIdx.x;
  for (int i = tid; i < 1024; i += 256) { s_idx[i] = tk_idx[i]; s_val[i] = tk_val[i]; }
  __syncthreads();
  const int e = tid;
  if (e >= E_) return;
  int c = 0;
  for (int i = 0; i < 1024; ++i) {
    if (s_idx[i] == e && c < 64) {
      ltok[e*64 + c]  = i >> 2;
      lpair[e*64 + c] = i;
      lwt[e*64 + c]   = s_val[i];
      ++c;
    }
  }
  cnt[e] = c;
}

// ---------------- MEGA1: gu (660 blocks) + sh_gu (176 blocks) ----------------------
__global__ __launch_bounds__(256) void k_mega1(
    const ushort_t* __restrict__ xb,
    const float* __restrict__ wg_all, const float* __restrict__ wu_all,
    const int* __restrict__ cnt, const int* __restrict__ ltok,
    const float* __restrict__ lwt, ushort_t* __restrict__ act,
    const float* __restrict__ swg, const float* __restrict__ swu,
    ushort_t* __restrict__ acts)
{
  __shared__ char smem[65536];
  float* lds = (float*)smem;
  const int bid = blockIdx.x;
  const int tid = threadIdx.x, wave = tid >> 6, lane = tid & 63;
  const int ln15 = lane & 15, kg = lane >> 4;

  if (bid < 660) {
    // ---- expert gate/up: N=128, BK=32, 2 LDS bufs of 32KB (R6-proven config) ----
    const int e  = bid / 11;
    const int cx = bid % 11;
    int m = cnt[e];
    if (m == 0) return;
    if (m > 64) m = 64;
    const int col0 = cx * 128;
    const size_t wbase = (size_t)e * ((size_t)H_ * F_) + col0;
    const float* gsg = wg_all + wbase + (size_t)(lane >> 5) * F_ + (lane & 31) * 4;
    const float* gsu = wu_all + wbase + (size_t)(lane >> 5) * F_ + (lane & 31) * 4;
    const int r0 = wave * 8;

    const ushort_t* ap[4];
    #pragma unroll
    for (int rt = 0; rt < 4; ++rt) {
      int row = rt*16 + ln15;
      int tok = ltok[e*64 + (row < m ? row : m-1)];
      ap[rt] = xb + (size_t)tok * H_ + kg*8;
    }

    f32x4 ag[4][2], au[4][2];
    #pragma unroll
    for (int i = 0; i < 4; ++i) { ag[i][0]=zero4(); ag[i][1]=zero4(); au[i][0]=zero4(); au[i][1]=zero4(); }
    bf16x8 a0[4], a1[4];

#define GU_STAGE(B, K0) do { \
    _Pragma("unroll") for (int i2 = 0; i2 < 4; ++i2) { \
      int r_ = r0 + i2*2; \
      gload16(gsg + (size_t)(K0 + r_) * F_, lds + (B)*8192 + r_*128); \
      gload16(gsu + (size_t)(K0 + r_) * F_, lds + (B)*8192 + 4096 + r_*128); \
    } } while(0)
#define GU_ALOAD(D, K0) do { \
    _Pragma("unroll") for (int rt = 0; rt < 4; ++rt) D[rt] = loada(ap[rt] + (K0)); } while(0)
#define GU_COMPUTE(B, A) do { \
    const float* lg_ = lds + (B)*8192 + kg*1024 + wave*32 + ln15; \
    bf16x8 bg0_ = ldsbS(lg_, 128), bg1_ = ldsbS(lg_ + 16, 128); \
    bf16x8 bu0_ = ldsbS(lg_ + 4096, 128), bu1_ = ldsbS(lg_ + 4112, 128); \
    _Pragma("unroll") for (int rt = 0; rt < 4; ++rt) { \
      ag[rt][0] = MFMA(A[rt], bg0_, ag[rt][0]); \
      ag[rt][1] = MFMA(A[rt], bg1_, ag[rt][1]); \
      au[rt][0] = MFMA(A[rt], bu0_, au[rt][0]); \
      au[rt][1] = MFMA(A[rt], bu1_, au[rt][1]); \
    } } while(0)

    GU_ALOAD(a0, 0);  GU_STAGE(0, 0);
    GU_ALOAD(a1, 32); GU_STAGE(1, 32);
    for (int t = 0; t + 2 < 64; t += 2) {
      VMW(12); BARM(); SCH();
      GU_COMPUTE(0, a0);
      BARM();
      GU_ALOAD(a0, (t+2)*32); GU_STAGE(0, (t+2)*32);
      VMW(12); BARM(); SCH();
      GU_COMPUTE(1, a1);
      BARM();
      GU_ALOAD(a1, (t+3)*32); GU_STAGE(1, (t+3)*32);
    }
    VMW(12); BARM(); SCH();
    GU_COMPUTE(0, a0);
    VMW(0); BARM(); SCH();
    GU_COMPUTE(1, a1);

    #pragma unroll
    for (int rt = 0; rt < 4; ++rt)
      #pragma unroll
      for (int nt = 0; nt < 2; ++nt)
        #pragma unroll
        for (int j = 0; j < 4; ++j) {
          int r = rt*16 + kg*4 + j;
          if (r < m) {
            float wt = lwt[e*64 + r];
            float g = ag[rt][nt][j], u = au[rt][nt][j];
            float a = g / (1.f + __expf(-g)) * u * wt;
            act[((size_t)e*64 + r) * F_ + col0 + wave*32 + nt*16 + ln15] = rne1(a);
          }
        }
  } else {
    // ---- shared gate/up: M=256, N=32 (R6-proven config) ----
    const int sb = bid - 660;
    const int cb = sb * 32;
    const int rowb = wave * 64;
    const int r0 = wave * 8;
    const float* gsg = swg + (size_t)(lane >> 3) * FS_ + cb + (lane & 7) * 4;
    const float* gsu = swu + (size_t)(lane >> 3) * FS_ + cb + (lane & 7) * 4;

    const ushort_t* ap[4];
    #pragma unroll
    for (int rt = 0; rt < 4; ++rt)
      ap[rt] = xb + (size_t)(rowb + rt*16 + ln15) * H_ + kg*8;

    f32x4 ag[4][2], au[4][2];
    #pragma unroll
    for (int i = 0; i < 4; ++i) { ag[i][0]=zero4(); ag[i][1]=zero4(); au[i][0]=zero4(); au[i][1]=zero4(); }
    bf16x8 a0[4], a1[4];

#define SG_STAGE(B, K0) do { \
    gload16(gsg + (size_t)(K0 + r0) * FS_, lds + (B)*2048 + r0*32); \
    gload16(gsu + (size_t)(K0 + r0) * FS_, lds + (B)*2048 + 1024 + r0*32); \
  } while(0)
#define SG_ALOAD(D, K0) do { \
    _Pragma("unroll") for (int rt = 0; rt < 4; ++rt) D[rt] = loada(ap[rt] + (K0)); } while(0)
#define SG_COMPUTE(B, A) do { \
    const float* lg_ = lds + (B)*2048 + kg*256 + ln15; \
    bf16x8 bg0_ = ldsbS(lg_, 32), bg1_ = ldsbS(lg_ + 16, 32); \
    bf16x8 bu0_ = ldsbS(lg_ + 1024, 32), bu1_ = ldsbS(lg_ + 1040, 32); \
    _Pragma("unroll") for (int rt = 0; rt < 4; ++rt) { \
      ag[rt][0] = MFMA(A[rt], bg0_, ag[rt][0]); \
      ag[rt][1] = MFMA(A[rt], bg1_, ag[rt][1]); \
      au[rt][0] = MFMA(A[rt], bu0_, au[rt][0]); \
      au[rt][1] = MFMA(A[rt], bu1_, au[rt][1]); \
    } } while(0)

    SG_ALOAD(a0, 0);  SG_STAGE(0, 0);
    SG_ALOAD(a1, 32); SG_STAGE(1, 32);
    for (int t = 0; t + 2 < 64; t += 2) {
      VMW(6); BARM(); SCH();
      SG_COMPUTE(0, a0);
      BARM();
      SG_ALOAD(a0, (t+2)*32); SG_STAGE(0, (t+2)*32);
      VMW(6); BARM(); SCH();
      SG_COMPUTE(1, a1);
      BARM();
      SG_ALOAD(a1, (t+3)*32); SG_STAGE(1, (t+3)*32);
    }
    VMW(6); BARM(); SCH();
    SG_COMPUTE(0, a0);
    VMW(0); BARM(); SCH();
    SG_COMPUTE(1, a1);

    #pragma unroll
    for (int rt = 0; rt < 4; ++rt)
      #pragma unroll
      for (int nt = 0; nt < 2; ++nt)
        #pragma unroll
        for (int j = 0; j < 4; ++j) {
          int row = rowb + rt*16 + kg*4 + j;
          float g = ag[rt][nt][j], u = au[rt][nt][j];
          acts[(size_t)row * FS_ + cb + nt*16 + ln15] = rne1(g / (1.f + __expf(-g)) * u);
        }
  }
}

// ---------------- MEGA2: down (480 blocks, N=256) + sh_down (128 blocks) ----------
__global__ __launch_bounds__(256) void k_mega2(
    const ushort_t* __restrict__ act, const float* __restrict__ wd_all,
    const int* __restrict__ cnt, const int* __restrict__ lpair,
    float* __restrict__ out4,
    const ushort_t* __restrict__ acts, const float* __restrict__ swd,
    float* __restrict__ acc4)
{
  __shared__ char smem[65536];
  float* lds = (float*)smem;
  const int bid = blockIdx.x;
  const int tid = threadIdx.x, wave = tid >> 6, lane = tid & 63;
  const int ln15 = lane & 15, kg = lane >> 4;

  if (bid < 480) {
    // ---- expert down: N=256 (1KB chunks), BK=32, 2 bufs of 32KB ----
    const int e  = bid / 8;
    const int cx = bid % 8;
    int m = cnt[e];
    if (m == 0) return;
    if (m > 64) m = 64;
    __shared__ int s_pair[64];
    if (tid < 64) s_pair[tid] = (tid < m) ? lpair[e*64 + tid] : 0;
    const int col0 = cx * 256;
    const float* gsd = wd_all + (size_t)e * ((size_t)F_ * H_) + col0 + lane * 4;
    const int r0 = wave * 8;
    const int c0 = wave * 64;

    const ushort_t* ap[4];
    #pragma unroll
    for (int rt = 0; rt < 4; ++rt)
      ap[rt] = act + ((size_t)e*64 + rt*16 + ln15) * F_ + kg*8;

    f32x4 ac[4][4];
    #pragma unroll
    for (int i = 0; i < 4; ++i)
      #pragma unroll
      for (int c = 0; c < 4; ++c) ac[i][c] = zero4();
    bf16x8 a0[4], a1[4];

#define DN_STAGE(B, K0) do { \
    _Pragma("unroll") for (int i2 = 0; i2 < 8; ++i2) { \
      int r_ = r0 + i2; \
      gload16(gsd + (size_t)(K0 + r_) * H_, lds + (B)*8192 + r_*256); \
    } } while(0)
#define DN_ALOAD(D, K0) do { \
    _Pragma("unroll") for (int rt = 0; rt < 4; ++rt) D[rt] = loada(ap[rt] + (K0)); } while(0)
#define DN_COMPUTE(B, A) do { \
    const float* lw_ = lds + (B)*8192 + kg*2048 + c0 + ln15; \
    bf16x8 b0_ = ldsbS(lw_, 256),      b1_ = ldsbS(lw_ + 16, 256); \
    bf16x8 b2_ = ldsbS(lw_ + 32, 256), b3_ = ldsbS(lw_ + 48, 256); \
    _Pragma("unroll") for (int rt = 0; rt < 4; ++rt) { \
      ac[rt][0] = MFMA(A[rt], b0_, ac[rt][0]); \
      ac[rt][1] = MFMA(A[rt], b1_, ac[rt][1]); \
      ac[rt][2] = MFMA(A[rt], b2_, ac[rt][2]); \
      ac[rt][3] = MFMA(A[rt], b3_, ac[rt][3]); \
    } } while(0)

    DN_ALOAD(a0, 0);  DN_STAGE(0, 0);
    DN_ALOAD(a1, 32); DN_STAGE(1, 32);
    for (int t = 0; t + 2 < 44; t += 2) {
      VMW(12); BARM(); SCH();
      DN_COMPUTE(0, a0);
      BARM();
      DN_ALOAD(a0, (t+2)*32); DN_STAGE(0, (t+2)*32);
      VMW(12); BARM(); SCH();
      DN_COMPUTE(1, a1);
      BARM();
      DN_ALOAD(a1, (t+3)*32); DN_STAGE(1, (t+3)*32);
    }
    VMW(12); BARM(); SCH();
    DN_COMPUTE(0, a0);
    VMW(0); BARM(); SCH();
    DN_COMPUTE(1, a1);

    #pragma unroll
    for (int rt = 0; rt < 4; ++rt)
      #pragma unroll
      for (int c = 0; c < 4; ++c)
        #pragma unroll
        for (int j = 0; j < 4; ++j) {
          int r = rt*16 + kg*4 + j;
          if (r < m)
            out4[(size_t)s_pair[r] * H_ + col0 + c0 + c*16 + ln15] = ac[rt][c][j];
        }
  } else {
    // ---- shared down: M=256, N=64, K-split 4 (R6-proven config) ----
    const int sb = bid - 480;
    const int cb = (sb & 31) * 64;
    const int kh = sb >> 5;         // 0..3, k in [kh*1408, +1408)
    const int rowb = wave * 64;
    const int r0 = wave * 8;
    const float* gsd = swd + (size_t)(kh*1408) * H_ + cb
                     + (size_t)(lane >> 4) * H_ + (lane & 15) * 4;

    const ushort_t* ap[4];
    #pragma unroll
    for (int rt = 0; rt < 4; ++rt)
      ap[rt] = acts + (size_t)(rowb + rt*16 + ln15) * FS_ + kh*1408 + kg*8;

    f32x4 ac[4][4];
    #pragma unroll
    for (int i = 0; i < 4; ++i)
      #pragma unroll
      for (int c = 0; c < 4; ++c) ac[i][c] = zero4();
    bf16x8 a0[4], a1[4];

#define SD_STAGE(B, K0) do { \
    gload16(gsd + (size_t)(K0 + r0) * H_,     lds + (B)*2048 + r0*64); \
    gload16(gsd + (size_t)(K0 + r0 + 4) * H_, lds + (B)*2048 + (r0+4)*64); \
  } while(0)
#define SD_ALOAD(D, K0) do { \
    _Pragma("unroll") for (int rt = 0; rt < 4; ++rt) D[rt] = loada(ap[rt] + (K0)); } while(0)
#define SD_COMPUTE(B, A) do { \
    const float* lw_ = lds + (B)*2048 + kg*512 + ln15; \
    bf16x8 b0_ = ldsbS(lw_, 64),      b1_ = ldsbS(lw_ + 16, 64); \
    bf16x8 b2_ = ldsbS(lw_ + 32, 64), b3_ = ldsbS(lw_ + 48, 64); \
    _Pragma("unroll") for (int rt = 0; rt < 4; ++rt) { \
      ac[rt][0] = MFMA(A[rt], b0_, ac[rt][0]); \
      ac[rt][1] = MFMA(A[rt], b1_, ac[rt][1]); \
      ac[rt][2] = MFMA(A[rt], b2_, ac[rt][2]); \
      ac[rt][3] = MFMA(A[rt], b3_, ac[rt][3]); \
    } } while(0)

    SD_ALOAD(a0, 0);  SD_STAGE(0, 0);
    SD_ALOAD(a1, 32); SD_STAGE(1, 32);
    for (int t = 0; t + 2 < 44; t += 2) {
      VMW(6); BARM(); SCH();
      SD_COMPUTE(0, a0);
      BARM();
      SD_ALOAD(a0, (t+2)*32); SD_STAGE(0, (t+2)*32);
      VMW(6); BARM(); SCH();
      SD_COMPUTE(1, a1);
      BARM();
      SD_ALOAD(a1, (t+3)*32); SD_STAGE(1, (t+3)*32);
    }
    VMW(6); BARM(); SCH();
    SD_COMPUTE(0, a0);
    VMW(0); BARM(); SCH();
    SD_COMPUTE(1, a1);

    #pragma unroll
    for (int rt = 0; rt < 4; ++rt)
      #pragma unroll
      for (int c = 0; c < 4; ++c)
        #pragma unroll
        for (int j = 0; j < 4; ++j) {
          int row = rowb + rt*16 + kg*4 + j;
          acc4[((size_t)kh * T_ + row) * H_ + cb + c*16 + ln15] = ac[rt][c][j];
        }
  }
}

// ---------------- K5: combine ------------------------------------------------------
__global__ __launch_bounds__(256) void k_final(
    const float* __restrict__ acc4, const float* __restrict__ out4,
    const float* __restrict__ sig, float* __restrict__ out)
{
  const int idx = blockIdx.x * blockDim.x + threadIdx.x;
  const int t = idx >> 9;
  const int h = (idx & 511) * 4;
  float ox = 0.f, oy = 0.f, oz = 0.f, ow = 0.f;
  #pragma unroll
  for (int s = 0; s < 4; ++s) {
    const float4 v = *(const float4*)(acc4 + ((size_t)s * T_ + t) * H_ + h);
    ox += v.x; oy += v.y; oz += v.z; ow += v.w;
  }
  const float sg = sig[t];
  ox *= sg; oy *= sg; oz *= sg; ow *= sg;
  #pragma unroll
  for (int k = 0; k < 4; ++k) {
    const float4 e4 = *(const float4*)(out4 + (size_t)(t*4 + k) * H_ + h);
    ox += e4.x; oy += e4.y; oz += e4.z; ow += e4.w;
  }
  float4 o; o.x = ox; o.y = oy; o.z = oz; o.w = ow;
  *(float4*)(out + (size_t)t * H_ + h) = o;
}

// ---------------- launch -----------------------------------------------------------
extern "C" void kernel_launch(void* const* d_in, const int* in_sizes, int n_in,
                              void* d_out, int out_size, void* d_ws, size_t ws_size,
                              hipStream_t stream)
{
  (void)in_sizes; (void)n_in; (void)out_size; (void)ws_size;
  const float* x   = (const float*)d_in[0];
  const float* gw  = (const float*)d_in[1];
  const float* wg  = (const float*)d_in[2];
  const float* wu  = (const float*)d_in[3];
  const float* wd  = (const float*)d_in[4];
  const float* swg = (const float*)d_in[5];
  const float* swu = (const float*)d_in[6];
  const float* swd = (const float*)d_in[7];
  const float* sgw = (const float*)d_in[8];

  char* ws = (char*)d_ws;
  ushort_t* xb    = (ushort_t*)(ws);                 // 1,048,576
  ushort_t* act   = (ushort_t*)(ws + 1048576);       // 10,813,440
  ushort_t* acts  = (ushort_t*)(ws + 11862016);      // 2,883,584
  float*    out4  = (float*)   (ws + 14745600);      // 8,388,608
  float*    acc4  = (float*)   (ws + 23134208);      // 8,388,608
  float*    sig   = (float*)   (ws + 31522816);      // 1,024
  int*      tkidx = (int*)     (ws + 31523840);      // 4,096
  float*    tkval = (float*)   (ws + 31527936);      // 4,096
  int*      cnt   = (int*)     (ws + 31532032);      // 256
  int*      ltok  = (int*)     (ws + 31532288);      // 15,360
  int*      lpair = (int*)     (ws + 31547648);      // 15,360
  float*    lwt   = (float*)   (ws + 31563008);      // 15,360

  k_router<<<T_, 256, 0, stream>>>(x, gw, sgw, xb, tkidx, tkval, sig);
  k_lists <<<1, 256, 0, stream>>>(tkidx, tkval, cnt, ltok, lpair, lwt);
  k_mega1 <<<660 + 176, 256, 0, stream>>>(xb, wg, wu, cnt, ltok, lwt, act, swg, swu, acts);
  k_mega2 <<<480 + 128, 256, 0, stream>>>(act, wd, cnt, lpair, out4, acts, swd, acc4);
  k_final <<<512, 256, 0, stream>>>(acc4, out4, sig, (float*)d_out);
}